// Round 4
// baseline (2299.503 us; speedup 1.0000x reference)
//
#include <hip/hip_runtime.h>
#include <hip/hip_bf16.h>
#include <stdint.h>
#include <stddef.h>

#define LAYERS 8
#define NCH 256
#define NMEL 640
#define NBATCH 16
#define SEQT 4096
#define BTROWS (NBATCH * SEQT)   // 65536
#define PADT 128
#define TPAD (SEQT + 2 * PADT)   // 4352
#define KX 1408                  // 3*256 + 640

typedef __hip_bfloat16 bf16;
typedef __attribute__((ext_vector_type(8))) short short8;
typedef __attribute__((ext_vector_type(4))) float f32x4;

__device__ __forceinline__ void g2l16(const void* g, void* l) {
  __builtin_amdgcn_global_load_lds(
      (const __attribute__((address_space(1))) unsigned int*)g,
      (__attribute__((address_space(3))) unsigned int*)l, 16, 0, 0);
}

#define VM12()  asm volatile("s_waitcnt vmcnt(12)" ::: "memory")
#define VM8()   asm volatile("s_waitcnt vmcnt(8)"  ::: "memory")
#define VM4()   asm volatile("s_waitcnt vmcnt(4)"  ::: "memory")
#define VM0()   asm volatile("s_waitcnt vmcnt(0)"  ::: "memory")
#define LGKM0() asm volatile("s_waitcnt lgkmcnt(0)" ::: "memory")

__device__ __forceinline__ float fsigmoid(float x) { return 1.f / (1.f + __expf(-x)); }
__device__ __forceinline__ float ftanh_(float x) { return 1.f - 2.f / (__expf(2.f * x) + 1.f); }

// ---------------------------------------------------------------------------
// GEMM1: x = [h(t-d); h(t); h(t+d); spect] @ Wstack^T ; acts = tanh(x1)*sig(x2)
// 256 rows x (128 tanh + 128 paired sigmoid cols). 8 waves (4m x 2n).
// 4-slot LDS ring (BK=32 per slot), prefetch depth 3, counted vmcnt(12).
// launch_bounds(512,2): 256 unified regs/wave -- accumulators MUST NOT spill.
// ---------------------------------------------------------------------------
__global__ __launch_bounds__(512, 2) void gemm1_kernel(
    const bf16* __restrict__ hpad, const bf16* __restrict__ spect,
    const bf16* __restrict__ wx,   // [512][1408] this layer, n-major
    const float* __restrict__ xb,  // [512] combined in_b + cond_b
    bf16* __restrict__ acts, int dil)
{
  // per slot (shorts): A [4][256][8]=8192, B1 [4][128][8]=4096, B2 4096
  __shared__ alignas(16) short lds[4 * 16384];   // 128 KB

  const int tid  = threadIdx.x;
  const int lane = tid & 63;
  const int wid  = tid >> 6;
  const int wm   = wid >> 1;          // 0..3
  const int wn   = wid & 1;           // 0..1

  // bijective XCD swizzle over 512 wgs: pairs (x, y=0/1) co-resident per XCD
  const int wg  = blockIdx.x;
  const int swz = ((wg & 7) << 6) | (wg >> 3);
  const int m0 = (swz >> 1) * 256;
  const int c0 = (swz & 1) * 128;     // tanh channel tile: 0 or 128
  const int b  = m0 >> 12;            // tile fully inside one batch
  const int t0 = m0 & (SEQT - 1);

  const f32x4 fzero = {0.f, 0.f, 0.f, 0.f};
  f32x4 acc1[4][4], acc2[4][4];
#pragma unroll
  for (int i = 0; i < 4; ++i)
#pragma unroll
    for (int j = 0; j < 4; ++j) { acc1[i][j] = fzero; acc2[i][j] = fzero; }

  // staging decomposition
  const int rA  = tid & 255;          // A row in tile
  const int kcA = tid >> 8;           // 0,1 -> chunks kcA, kcA+2
  const int rB  = tid & 127;          // B row (output col in 128-tile)
  const int kcB = tid >> 7;           // 0..3

  const bf16* hbase  = hpad + ((size_t)(b * TPAD + PADT + t0 + rA)) * NCH + kcA * 8;
  const bf16* sbase  = spect + (size_t)(m0 + rA) * NMEL + kcA * 8;
  const bf16* b1base = wx + (size_t)(c0 + rB) * KX + kcB * 8;
  const bf16* b2base = b1base + (size_t)256 * KX;
  const ptrdiff_t dilN = (ptrdiff_t)dil * NCH;

  auto stage = [&](int kt) {
    short* base = lds + (kt & 3) * 16384;
    const bf16* a0;
    if (kt < 24) {
      const int tap = kt >> 3;
      const int ch  = (kt & 7) << 5;
      a0 = hbase + (ptrdiff_t)(tap - 1) * dilN + ch;
    } else {
      a0 = sbase + ((kt - 24) << 5);
    }
    g2l16(a0,      base + (kcA * 256 + rA) * 8);
    g2l16(a0 + 16, base + ((kcA + 2) * 256 + rA) * 8);
    g2l16(b1base + kt * 32, base + 8192  + (kcB * 128 + rB) * 8);
    g2l16(b2base + kt * 32, base + 12288 + (kcB * 128 + rB) * 8);
  };

  const int rl = lane & 15;
  const int kc = lane >> 4;

  auto chunk = [&](int kt, int pf, auto vmwait) {
    if (pf >= 0) stage(pf);
    vmwait();
    __builtin_amdgcn_s_barrier();      // slot (kt&3) fully staged for all waves

    const short* cur = lds + (kt & 3) * 16384;
    short8 af[4], bfa[4], bfb[4];
#pragma unroll
    for (int f = 0; f < 4; ++f) {
      af[f]  = *(const short8*)(cur + (kc * 256 + wm * 64 + f * 16 + rl) * 8);
      bfa[f] = *(const short8*)(cur + 8192  + (kc * 128 + wn * 64 + f * 16 + rl) * 8);
      bfb[f] = *(const short8*)(cur + 12288 + (kc * 128 + wn * 64 + f * 16 + rl) * 8);
    }
    LGKM0();
    __builtin_amdgcn_sched_barrier(0);
    __builtin_amdgcn_s_setprio(1);
#pragma unroll
    for (int i = 0; i < 4; ++i)
#pragma unroll
      for (int j = 0; j < 4; ++j) {
        acc1[i][j] = __builtin_amdgcn_mfma_f32_16x16x32_bf16(af[i], bfa[j], acc1[i][j], 0, 0, 0);
        acc2[i][j] = __builtin_amdgcn_mfma_f32_16x16x32_bf16(af[i], bfb[j], acc2[i][j], 0, 0, 0);
      }
    __builtin_amdgcn_s_setprio(0);
    __builtin_amdgcn_s_barrier();      // reads of this slot done before reuse
  };

  stage(0); stage(1); stage(2);
  for (int t = 0; t < 41; ++t) chunk(t, t + 3, [] { VM12(); });
  chunk(41, -1, [] { VM8(); });
  chunk(42, -1, [] { VM4(); });
  chunk(43, -1, [] { VM0(); });

  const int rl2 = lane & 15;
  const int ro  = (lane >> 4) * 4;
#pragma unroll
  for (int i = 0; i < 4; ++i) {
#pragma unroll
    for (int j = 0; j < 4; ++j) {
      const int col = c0 + wn * 64 + j * 16 + rl2;   // tanh channel, [0,256)
      const float bx1 = xb[col];
      const float bx2 = xb[col + 256];
#pragma unroll
      for (int r = 0; r < 4; ++r) {
        const int m = m0 + wm * 64 + i * 16 + ro + r;
        const float x1 = acc1[i][j][r] + bx1;
        const float x2 = acc2[i][j][r] + bx2;
        acts[(size_t)m * NCH + col] = __float2bfloat16(ftanh_(x1) * fsigmoid(x2));
      }
    }
  }
}

// ---------------------------------------------------------------------------
// GEMM2: rs = acts @ Wr^T (+rb); n-half 0 -> h += rs ; half 1 -> skip (+)= rs
// 256 rows x 256 cols, 8 waves (4m x 2n), each wave 64x128. Same ring-4.
// ---------------------------------------------------------------------------
__global__ __launch_bounds__(512, 2) void gemm2_kernel(
    const bf16* __restrict__ acts, const bf16* __restrict__ wr,  // [512][256]
    const float* __restrict__ rb, bf16* __restrict__ hpad,
    float* __restrict__ skip, const int first)
{
  // per slot (shorts): A [4][256][8]=8192, B [4][256][8]=8192
  __shared__ alignas(16) short lds[4 * 16384];   // 128 KB

  const int tid  = threadIdx.x;
  const int lane = tid & 63;
  const int wid  = tid >> 6;
  const int wm   = wid >> 1;          // 0..3
  const int wn   = wid & 1;           // 0..1

  const int wg  = blockIdx.x;
  const int swz = ((wg & 7) << 6) | (wg >> 3);
  const int m0 = (swz >> 1) * 256;
  const int n0 = (swz & 1) * 256;     // 0 (h-update) or 256 (skip)
  const int b  = m0 >> 12;

  const f32x4 fzero = {0.f, 0.f, 0.f, 0.f};
  f32x4 acc[4][8];
#pragma unroll
  for (int i = 0; i < 4; ++i)
#pragma unroll
    for (int j = 0; j < 8; ++j) acc[i][j] = fzero;

  const int rA  = tid & 255;
  const int kcA = tid >> 8;           // 0,1

  const bf16* pA = acts + (size_t)(m0 + rA) * NCH + kcA * 8;
  const bf16* pB = wr + (size_t)(n0 + rA) * NCH + kcA * 8;

  auto stage = [&](int kt) {
    short* base = lds + (kt & 3) * 16384;
    g2l16(pA + kt * 32,      base + (kcA * 256 + rA) * 8);
    g2l16(pA + kt * 32 + 16, base + ((kcA + 2) * 256 + rA) * 8);
    g2l16(pB + kt * 32,      base + 8192 + (kcA * 256 + rA) * 8);
    g2l16(pB + kt * 32 + 16, base + 8192 + ((kcA + 2) * 256 + rA) * 8);
  };

  const int rl = lane & 15;
  const int kc = lane >> 4;

  auto chunk = [&](int kt, int pf, auto vmwait) {
    if (pf >= 0) stage(pf);
    vmwait();
    __builtin_amdgcn_s_barrier();

    const short* cur = lds + (kt & 3) * 16384;
    short8 af[4], bfr[8];
#pragma unroll
    for (int f = 0; f < 4; ++f)
      af[f] = *(const short8*)(cur + (kc * 256 + wm * 64 + f * 16 + rl) * 8);
#pragma unroll
    for (int j = 0; j < 8; ++j)
      bfr[j] = *(const short8*)(cur + 8192 + (kc * 256 + wn * 128 + j * 16 + rl) * 8);
    LGKM0();
    __builtin_amdgcn_sched_barrier(0);
    __builtin_amdgcn_s_setprio(1);
#pragma unroll
    for (int i = 0; i < 4; ++i)
#pragma unroll
      for (int j = 0; j < 8; ++j)
        acc[i][j] = __builtin_amdgcn_mfma_f32_16x16x32_bf16(af[i], bfr[j], acc[i][j], 0, 0, 0);
    __builtin_amdgcn_s_setprio(0);
    __builtin_amdgcn_s_barrier();
  };

  stage(0); stage(1); stage(2);
  for (int t = 0; t < 5; ++t) chunk(t, t + 3, [] { VM12(); });
  chunk(5, -1, [] { VM8(); });
  chunk(6, -1, [] { VM4(); });
  chunk(7, -1, [] { VM0(); });

  const int rl2 = lane & 15;
  const int ro  = (lane >> 4) * 4;
#pragma unroll
  for (int i = 0; i < 4; ++i) {
#pragma unroll
    for (int j = 0; j < 8; ++j) {
      const int n = n0 + wn * 128 + j * 16 + rl2;
      const float bias = rb[n];
#pragma unroll
      for (int r = 0; r < 4; ++r) {
        const int m = m0 + wm * 64 + i * 16 + ro + r;
        const float v = acc[i][j][r] + bias;
        if (n < NCH) {
          const size_t hi = ((size_t)(b * TPAD + PADT + (m & (SEQT - 1)))) * NCH + n;
          hpad[hi] = __float2bfloat16(__bfloat162float(hpad[hi]) + v);
        } else {
          const size_t si = (size_t)m * NCH + (n - NCH);
          if (first) skip[si] = v;
          else       skip[si] += v;
        }
      }
    }
  }
}

// ---------------------------------------------------------------------------
// aux kernels
// ---------------------------------------------------------------------------
__global__ void start_kernel(const float* __restrict__ audio, const float* __restrict__ sw,
                             const float* __restrict__ sb, bf16* __restrict__ hpad)
{
  const int idx = blockIdx.x * 256 + threadIdx.x;   // < 16777216
  const int m = idx >> 8;
  const int c = idx & 255;
  const int b = m >> 12;
  const int t = m & (SEQT - 1);
  const float* a = audio + (size_t)m * 4;
  float v = sb[c] + a[0] * sw[c] + a[1] * sw[256 + c] + a[2] * sw[512 + c] + a[3] * sw[768 + c];
  hpad[((size_t)(b * TPAD + PADT + t)) * NCH + c] = __float2bfloat16(v);
}

__global__ void cvt_spect_kernel(const float* __restrict__ s, bf16* __restrict__ d)
{
  const size_t i = ((size_t)blockIdx.x * 256 + threadIdx.x) * 4;
  const float4 v = *(const float4*)(s + i);
  bf16* o = d + i;
  o[0] = __float2bfloat16(v.x);
  o[1] = __float2bfloat16(v.y);
  o[2] = __float2bfloat16(v.z);
  o[3] = __float2bfloat16(v.w);
}

__global__ void prep_wx_kernel(const float* __restrict__ in_w, const float* __restrict__ cond_w,
                               bf16* __restrict__ wx)
{
  const size_t idx = (size_t)blockIdx.x * 256 + threadIdx.x;
  if (idx >= (size_t)LAYERS * 512 * KX) return;
  const int k = (int)(idx % KX);
  const int n = (int)((idx / KX) & 511);
  const int i = (int)(idx / ((size_t)512 * KX));
  float v;
  if (k < 768) {
    const int tap = k >> 8;
    const int c   = k & 255;
    v = in_w[(size_t)(((i * 3 + tap) << 8) + c) * 512 + n];
  } else {
    v = cond_w[(size_t)(i * NMEL + (k - 768)) * 512 + n];
  }
  wx[idx] = __float2bfloat16(v);
}

__global__ void prep_wr_kernel(const float* __restrict__ rs_w, const float* __restrict__ rs_w_last,
                               bf16* __restrict__ wr)
{
  const int idx = blockIdx.x * 256 + threadIdx.x;   // < 1048576
  const int k = idx & 255;
  const int n = (idx >> 8) & 511;
  const int i = idx >> 17;
  float v;
  if (i < LAYERS - 1) v = rs_w[(size_t)((i << 8) + k) * 512 + n];
  else                v = (n >= 256) ? rs_w_last[(k << 8) + (n - 256)] : 0.f;
  wr[idx] = __float2bfloat16(v);
}

__global__ void prep_bias_kernel(const float* __restrict__ in_b, const float* __restrict__ cond_b,
                                 const float* __restrict__ rs_b, const float* __restrict__ rs_b_last,
                                 float* __restrict__ xb, float* __restrict__ rb)
{
  const int idx = blockIdx.x * 256 + threadIdx.x;   // < 4096
  if (idx >= LAYERS * 512) return;
  const int i = idx >> 9;
  const int n = idx & 511;
  xb[idx] = in_b[idx] + cond_b[idx];
  rb[idx] = (i < LAYERS - 1) ? rs_b[idx] : ((n >= 256) ? rs_b_last[n - 256] : 0.f);
}

__global__ void end_kernel(const float* __restrict__ skip, const float* __restrict__ ew,
                           const float* __restrict__ eb, float* __restrict__ out)
{
  const int idx = blockIdx.x * 256 + threadIdx.x;   // < 524288
  const int m = idx >> 3;
  const int j = idx & 7;
  const float* srow = skip + (size_t)m * NCH;
  float s = eb[j];
#pragma unroll 4
  for (int c = 0; c < NCH; ++c) s += srow[c] * ew[c * 8 + j];
  out[idx] = s;
}

// ---------------------------------------------------------------------------
extern "C" void kernel_launch(void* const* d_in, const int* in_sizes, int n_in,
                              void* d_out, int out_size, void* d_ws, size_t ws_size,
                              hipStream_t stream)
{
  const float* audio     = (const float*)d_in[0];
  const float* spect     = (const float*)d_in[1];
  const float* start_w   = (const float*)d_in[2];
  const float* start_b   = (const float*)d_in[3];
  const float* in_w      = (const float*)d_in[4];
  const float* in_b      = (const float*)d_in[5];
  const float* cond_w    = (const float*)d_in[6];
  const float* cond_b    = (const float*)d_in[7];
  const float* rs_w      = (const float*)d_in[8];
  const float* rs_b      = (const float*)d_in[9];
  const float* rs_w_last = (const float*)d_in[10];
  const float* rs_b_last = (const float*)d_in[11];
  const float* end_w     = (const float*)d_in[12];
  const float* end_b     = (const float*)d_in[13];
  float* out = (float*)d_out;

  char* p = (char*)d_ws;
  bf16* spect_bf = (bf16*)p;  p += (size_t)BTROWS * NMEL * 2;          // 83.9 MB
  bf16* hpad     = (bf16*)p;  p += (size_t)NBATCH * TPAD * NCH * 2;    // 35.7 MB
  bf16* actsb    = (bf16*)p;  p += (size_t)BTROWS * NCH * 2;           // 33.6 MB
  float* skip    = (float*)p; p += (size_t)BTROWS * NCH * 4;           // 67.1 MB
  bf16* wx       = (bf16*)p;  p += (size_t)LAYERS * 512 * KX * 2;      // 11.5 MB
  bf16* wr       = (bf16*)p;  p += (size_t)LAYERS * 512 * 256 * 2;     //  2.1 MB
  float* xb      = (float*)p; p += (size_t)LAYERS * 512 * 4;
  float* rb      = (float*)p; p += (size_t)LAYERS * 512 * 4;
  if ((size_t)(p - (char*)d_ws) > ws_size) return;  // insufficient workspace

  hipMemsetAsync(hpad, 0, (size_t)NBATCH * TPAD * NCH * 2, stream);
  prep_wx_kernel<<<(LAYERS * 512 * KX + 255) / 256, 256, 0, stream>>>(in_w, cond_w, wx);
  prep_wr_kernel<<<(LAYERS * 512 * 256) / 256, 256, 0, stream>>>(rs_w, rs_w_last, wr);
  prep_bias_kernel<<<16, 256, 0, stream>>>(in_b, cond_b, rs_b, rs_b_last, xb, rb);
  cvt_spect_kernel<<<(BTROWS * NMEL / 4) / 256, 256, 0, stream>>>(spect, spect_bf);
  start_kernel<<<(BTROWS * NCH) / 256, 256, 0, stream>>>(audio, start_w, start_b, hpad);

  for (int i = 0; i < LAYERS; ++i) {
    gemm1_kernel<<<512, 512, 0, stream>>>(hpad, spect_bf, wx + (size_t)i * 512 * KX,
                                          xb + i * 512, actsb, 1 << i);
    gemm2_kernel<<<512, 512, 0, stream>>>(actsb, wr + (size_t)i * 512 * 256,
                                          rb + i * 512, hpad, skip, i == 0 ? 1 : 0);
  }
  end_kernel<<<(BTROWS * 8) / 256, 256, 0, stream>>>(skip, end_w, end_b, out);
}

// Round 5
// 1716.388 us; speedup vs baseline: 1.3397x; 1.3397x over previous
//
#include <hip/hip_runtime.h>
#include <hip/hip_bf16.h>
#include <stdint.h>
#include <stddef.h>

#define LAYERS 8
#define NCH 256
#define NMEL 640
#define NBATCH 16
#define SEQT 4096
#define BTROWS (NBATCH * SEQT)   // 65536
#define PADT 128
#define TPAD (SEQT + 2 * PADT)   // 4352
#define KX 1408                  // 3*256 + 640

// NC8 layouts (all bf16, inner dim = 8 channels/k):
//  hpad : [b][32 cc][TPAD t][8]
//  spect: [b][80 cc][4096 t][8]
//  acts : [b][32 cc][4096 t][8]
//  wx   : [layer][44 kt][4 kc][512 n][8]
//  wr   : [layer][ 8 kt][4 kc][512 n][8]

typedef __hip_bfloat16 bf16;
typedef __attribute__((ext_vector_type(8))) short short8;
typedef __attribute__((ext_vector_type(4))) float f32x4;

__device__ __forceinline__ void g2l16(const void* g, void* l) {
  __builtin_amdgcn_global_load_lds(
      (const __attribute__((address_space(1))) unsigned int*)g,
      (__attribute__((address_space(3))) unsigned int*)l, 16, 0, 0);
}

#define VM12()  asm volatile("s_waitcnt vmcnt(12)" ::: "memory")
#define VM8()   asm volatile("s_waitcnt vmcnt(8)"  ::: "memory")
#define VM4()   asm volatile("s_waitcnt vmcnt(4)"  ::: "memory")
#define VM0()   asm volatile("s_waitcnt vmcnt(0)"  ::: "memory")
#define LGKM0() asm volatile("s_waitcnt lgkmcnt(0)" ::: "memory")

__device__ __forceinline__ float fsigmoid(float x) { return 1.f / (1.f + __expf(-x)); }
__device__ __forceinline__ float ftanh_(float x) { return 1.f - 2.f / (__expf(2.f * x) + 1.f); }

// ---------------------------------------------------------------------------
// GEMM1: x = [h(t-d); h(t); h(t+d); spect] @ Wstack^T ; acts = tanh(x1)*sig(x2)
// 256 rows x (128 tanh + 128 paired sigmoid cols). 8 waves (4m x 2n).
// 4-slot LDS ring (BK=32/slot), depth-3 prefetch, counted vmcnt. NC8 staging:
// every global_load_lds is 64 lanes x 16B fully contiguous (1 KB/instr).
// ---------------------------------------------------------------------------
__global__ __launch_bounds__(512, 2) void gemm1_kernel(
    const bf16* __restrict__ hpad, const bf16* __restrict__ spect,
    const bf16* __restrict__ wx,   // this layer: [44][4][512][8]
    const float* __restrict__ xb,  // [512] combined in_b + cond_b
    bf16* __restrict__ acts, int dil)
{
  // per slot (shorts): A [4 kc][256 t][8]=8192, B1 [4][128][8]=4096, B2 4096
  __shared__ alignas(16) short lds[4 * 16384];   // 128 KB

  const int tid  = threadIdx.x;
  const int lane = tid & 63;
  const int wid  = tid >> 6;
  const int wm   = wid >> 1;          // 0..3
  const int wn   = wid & 1;           // 0..1

  const int wg  = blockIdx.x;
  const int swz = ((wg & 7) << 6) | (wg >> 3);   // bijective on [0,512)
  const int m0 = (swz >> 1) * 256;
  const int c0 = (swz & 1) * 128;     // tanh channel tile: 0 or 128
  const int b  = m0 >> 12;            // tile fully inside one batch
  const int t0 = m0 & (SEQT - 1);

  const f32x4 fzero = {0.f, 0.f, 0.f, 0.f};
  f32x4 acc1[4][4], acc2[4][4];
#pragma unroll
  for (int i = 0; i < 4; ++i)
#pragma unroll
    for (int j = 0; j < 4; ++j) { acc1[i][j] = fzero; acc2[i][j] = fzero; }

  // staging decomposition: A by (ccA, tA), B by (kcB, nB); lanes contiguous
  const int tA  = tid & 127;          // t_local (2 loads: tA, tA+128)
  const int ccA = tid >> 7;           // k sub-chunk 0..3
  const int nB  = tid & 127;          // B col local
  const int kcB = tid >> 7;           // 0..3

  const bf16* pAh = hpad  + (((size_t)b * 32 + ccA) * TPAD + PADT + t0 + tA) * 8;
  const bf16* pAs = spect + (((size_t)b * 80 + ccA) * 4096 + t0 + tA) * 8;
  const bf16* pB  = wx + ((size_t)(kcB * 512) + c0 + nB) * 8;
  const ptrdiff_t dil8 = (ptrdiff_t)dil * 8;

  short* dA  = nullptr;  // per-slot offsets computed in stage
  auto stage = [&](int kt) {
    short* base = lds + (kt & 3) * 16384;
    const bf16* a0;
    if (kt < 24) {
      const int tap = kt >> 3;                       // 0,1,2
      a0 = pAh + (ptrdiff_t)((kt & 7) * 4) * TPAD * 8 + (ptrdiff_t)(tap - 1) * dil8;
    } else {
      a0 = pAs + (ptrdiff_t)(kt - 24) * 131072;      // 4*4096*8
    }
    const bf16* w1 = pB + (ptrdiff_t)kt * 16384;     // 4*512*8
    g2l16(a0,        base + (ccA * 256 + tA) * 8);
    g2l16(a0 + 1024, base + (ccA * 256 + tA + 128) * 8);   // +128 t
    g2l16(w1,        base + 8192  + (kcB * 128 + nB) * 8);
    g2l16(w1 + 2048, base + 12288 + (kcB * 128 + nB) * 8); // +256 cols
  };
  (void)dA;

  const int rl = lane & 15;
  const int kc = lane >> 4;

  auto chunk = [&](int kt, int pf, auto vmwait) {
    if (pf >= 0) stage(pf);
    vmwait();
    __builtin_amdgcn_s_barrier();      // slot (kt&3) fully staged

    const short* cur = lds + (kt & 3) * 16384;
    short8 af[4], bfa[4], bfb[4];
#pragma unroll
    for (int f = 0; f < 4; ++f) {
      af[f]  = *(const short8*)(cur + (kc * 256 + wm * 64 + f * 16 + rl) * 8);
      bfa[f] = *(const short8*)(cur + 8192  + (kc * 128 + wn * 64 + f * 16 + rl) * 8);
      bfb[f] = *(const short8*)(cur + 12288 + (kc * 128 + wn * 64 + f * 16 + rl) * 8);
    }
    LGKM0();
    __builtin_amdgcn_sched_barrier(0);
    __builtin_amdgcn_s_setprio(1);
#pragma unroll
    for (int i = 0; i < 4; ++i)
#pragma unroll
      for (int j = 0; j < 4; ++j) {
        acc1[i][j] = __builtin_amdgcn_mfma_f32_16x16x32_bf16(af[i], bfa[j], acc1[i][j], 0, 0, 0);
        acc2[i][j] = __builtin_amdgcn_mfma_f32_16x16x32_bf16(af[i], bfb[j], acc2[i][j], 0, 0, 0);
      }
    __builtin_amdgcn_s_setprio(0);
    __builtin_amdgcn_s_barrier();      // slot reads done before reuse
  };

  stage(0); stage(1); stage(2);
  for (int t = 0; t < 41; ++t) chunk(t, t + 3, [] { VM12(); });
  chunk(41, -1, [] { VM8(); });
  chunk(42, -1, [] { VM4(); });
  chunk(43, -1, [] { VM0(); });

  const int rl2 = lane & 15;
  const int ro  = (lane >> 4) * 4;
#pragma unroll
  for (int i = 0; i < 4; ++i) {
#pragma unroll
    for (int j = 0; j < 4; ++j) {
      const int col = c0 + wn * 64 + j * 16 + rl2;   // tanh channel, [0,256)
      const float bx1 = xb[col];
      const float bx2 = xb[col + 256];
      bf16* arow = acts + (((size_t)b * 32 + (col >> 3)) * 4096) * 8 + (col & 7);
#pragma unroll
      for (int r = 0; r < 4; ++r) {
        const int t = t0 + wm * 64 + i * 16 + ro + r;
        const float x1 = acc1[i][j][r] + bx1;
        const float x2 = acc2[i][j][r] + bx2;
        arow[(size_t)t * 8] = __float2bfloat16(ftanh_(x1) * fsigmoid(x2));
      }
    }
  }
}

// ---------------------------------------------------------------------------
// GEMM2: rs = acts @ Wr^T (+rb); n-half 0 -> h += rs ; half 1 -> skip (+)= rs
// 256 rows x 256 cols, 8 waves (4m x 2n), wave 64x128. Same ring-4, NC8.
// ---------------------------------------------------------------------------
__global__ __launch_bounds__(512, 2) void gemm2_kernel(
    const bf16* __restrict__ acts, const bf16* __restrict__ wr,  // [8][4][512][8]
    const float* __restrict__ rb, bf16* __restrict__ hpad,
    float* __restrict__ skip, const int first)
{
  // per slot (shorts): A [4][256][8]=8192, B [4][256][8]=8192
  __shared__ alignas(16) short lds[4 * 16384];   // 128 KB

  const int tid  = threadIdx.x;
  const int lane = tid & 63;
  const int wid  = tid >> 6;
  const int wm   = wid >> 1;          // 0..3
  const int wn   = wid & 1;           // 0..1

  const int wg  = blockIdx.x;
  const int swz = ((wg & 7) << 6) | (wg >> 3);
  const int m0 = (swz >> 1) * 256;
  const int n0 = (swz & 1) * 256;     // 0 (h-update) or 256 (skip)
  const int b  = m0 >> 12;
  const int t0 = m0 & (SEQT - 1);

  const f32x4 fzero = {0.f, 0.f, 0.f, 0.f};
  f32x4 acc[4][8];
#pragma unroll
  for (int i = 0; i < 4; ++i)
#pragma unroll
    for (int j = 0; j < 8; ++j) acc[i][j] = fzero;

  const int tA   = tid & 127;
  const int ccA  = tid >> 7;          // 0..3
  const int nB2  = tid & 255;
  const int kcB2 = tid >> 8;          // 0..1 (loads kcB2 and kcB2+2)

  const bf16* pA = acts + (((size_t)b * 32 + ccA) * 4096 + t0 + tA) * 8;
  const bf16* pB = wr + ((size_t)(kcB2 * 512) + n0 + nB2) * 8;

  auto stage = [&](int kt) {
    short* base = lds + (kt & 3) * 16384;
    const bf16* a0 = pA + (ptrdiff_t)kt * 131072;    // 4*4096*8
    const bf16* w0 = pB + (ptrdiff_t)kt * 16384;     // 4*512*8
    g2l16(a0,        base + (ccA * 256 + tA) * 8);
    g2l16(a0 + 1024, base + (ccA * 256 + tA + 128) * 8);
    g2l16(w0,        base + 8192 + (kcB2 * 256 + nB2) * 8);
    g2l16(w0 + 8192, base + 8192 + ((kcB2 + 2) * 256 + nB2) * 8);  // +2 kc
  };

  const int rl = lane & 15;
  const int kc = lane >> 4;

  auto chunk = [&](int kt, int pf, auto vmwait) {
    if (pf >= 0) stage(pf);
    vmwait();
    __builtin_amdgcn_s_barrier();

    const short* cur = lds + (kt & 3) * 16384;
    short8 af[4], bfr[8];
#pragma unroll
    for (int f = 0; f < 4; ++f)
      af[f] = *(const short8*)(cur + (kc * 256 + wm * 64 + f * 16 + rl) * 8);
#pragma unroll
    for (int j = 0; j < 8; ++j)
      bfr[j] = *(const short8*)(cur + 8192 + (kc * 256 + wn * 128 + j * 16 + rl) * 8);
    LGKM0();
    __builtin_amdgcn_sched_barrier(0);
    __builtin_amdgcn_s_setprio(1);
#pragma unroll
    for (int i = 0; i < 4; ++i)
#pragma unroll
      for (int j = 0; j < 8; ++j)
        acc[i][j] = __builtin_amdgcn_mfma_f32_16x16x32_bf16(af[i], bfr[j], acc[i][j], 0, 0, 0);
    __builtin_amdgcn_s_setprio(0);
    __builtin_amdgcn_s_barrier();
  };

  stage(0); stage(1); stage(2);
  for (int t = 0; t < 5; ++t) chunk(t, t + 3, [] { VM12(); });
  chunk(5, -1, [] { VM8(); });
  chunk(6, -1, [] { VM4(); });
  chunk(7, -1, [] { VM0(); });

  const int rl2 = lane & 15;
  const int ro  = (lane >> 4) * 4;
#pragma unroll
  for (int i = 0; i < 4; ++i) {
#pragma unroll
    for (int j = 0; j < 8; ++j) {
      const int n = n0 + wn * 128 + j * 16 + rl2;
      const float bias = rb[n];
#pragma unroll
      for (int r = 0; r < 4; ++r) {
        const int t = t0 + wm * 64 + i * 16 + ro + r;
        const float v = acc[i][j][r] + bias;
        if (n < NCH) {
          bf16* hp = hpad + ((((size_t)b * 32 + (n >> 3)) * TPAD + PADT + t) * 8) + (n & 7);
          *hp = __float2bfloat16(__bfloat162float(*hp) + v);
        } else {
          const size_t si = ((size_t)(b * SEQT + t)) * NCH + (n - NCH);
          if (first) skip[si] = v;
          else       skip[si] += v;
        }
      }
    }
  }
}

// ---------------------------------------------------------------------------
// aux kernels
// ---------------------------------------------------------------------------
__global__ void start_kernel(const float* __restrict__ audio, const float* __restrict__ sw,
                             const float* __restrict__ sb, bf16* __restrict__ hpad)
{
  const int idx = blockIdx.x * 256 + threadIdx.x;   // < 16777216
  const int w  = idx & 7;
  const int t  = (idx >> 3) & 4095;
  const int cc = (idx >> 15) & 31;
  const int b  = idx >> 20;
  const int c  = cc * 8 + w;
  const float* a = audio + ((size_t)(b * SEQT + t)) * 4;
  float v = sb[c] + a[0] * sw[c] + a[1] * sw[256 + c] + a[2] * sw[512 + c] + a[3] * sw[768 + c];
  hpad[(((size_t)b * 32 + cc) * TPAD + PADT + t) * 8 + w] = __float2bfloat16(v);
}

__global__ void cvt_spect_kernel(const float* __restrict__ s, bf16* __restrict__ d)
{
  const size_t idx = (size_t)blockIdx.x * 256 + threadIdx.x;  // < 41943040
  const int w  = (int)(idx & 7);
  const int t  = (int)((idx >> 3) & 4095);
  const unsigned q = (unsigned)(idx >> 15);     // b*80 + cc
  const int b  = q / 80;
  const int cc = q % 80;
  const int c  = cc * 8 + w;
  d[idx] = __float2bfloat16(s[((size_t)(b * SEQT + t)) * NMEL + c]);
}

__global__ void prep_wx_kernel(const float* __restrict__ in_w, const float* __restrict__ cond_w,
                               bf16* __restrict__ wx)
{
  const size_t idx = (size_t)blockIdx.x * 256 + threadIdx.x;
  if (idx >= (size_t)LAYERS * 44 * 4 * 512 * 8) return;
  const int w   = (int)(idx & 7);
  const int n   = (int)((idx >> 3) & 511);
  const int kc  = (int)((idx >> 12) & 3);
  const unsigned ktp = (unsigned)(idx >> 14);   // i*44 + kt
  const int i  = ktp / 44;
  const int kt = ktp % 44;
  const int k  = kt * 32 + kc * 8 + w;
  float v;
  if (k < 768) {
    const int tap = k >> 8;
    const int c   = k & 255;
    v = in_w[(size_t)(((i * 3 + tap) << 8) + c) * 512 + n];
  } else {
    v = cond_w[((size_t)i * NMEL + (k - 768)) * 512 + n];
  }
  wx[idx] = __float2bfloat16(v);
}

__global__ void prep_wr_kernel(const float* __restrict__ rs_w, const float* __restrict__ rs_w_last,
                               bf16* __restrict__ wr)
{
  const int idx = blockIdx.x * 256 + threadIdx.x;   // < 1048576
  const int w  = idx & 7;
  const int n  = (idx >> 3) & 511;
  const int kc = (idx >> 12) & 3;
  const int kt = (idx >> 14) & 7;
  const int i  = idx >> 17;
  const int k  = kt * 32 + kc * 8 + w;              // [0,256)
  float v;
  if (i < LAYERS - 1) v = rs_w[(size_t)((i << 8) + k) * 512 + n];
  else                v = (n >= 256) ? rs_w_last[(k << 8) + (n - 256)] : 0.f;
  wr[idx] = __float2bfloat16(v);
}

__global__ void prep_bias_kernel(const float* __restrict__ in_b, const float* __restrict__ cond_b,
                                 const float* __restrict__ rs_b, const float* __restrict__ rs_b_last,
                                 float* __restrict__ xb, float* __restrict__ rb)
{
  const int idx = blockIdx.x * 256 + threadIdx.x;   // < 4096
  if (idx >= LAYERS * 512) return;
  const int i = idx >> 9;
  const int n = idx & 511;
  xb[idx] = in_b[idx] + cond_b[idx];
  rb[idx] = (i < LAYERS - 1) ? rs_b[idx] : ((n >= 256) ? rs_b_last[n - 256] : 0.f);
}

__global__ void end_kernel(const float* __restrict__ skip, const float* __restrict__ ew,
                           const float* __restrict__ eb, float* __restrict__ out)
{
  const int idx = blockIdx.x * 256 + threadIdx.x;   // < 524288
  const int m = idx >> 3;
  const int j = idx & 7;
  const float* srow = skip + (size_t)m * NCH;
  float s = eb[j];
#pragma unroll 4
  for (int c = 0; c < NCH; ++c) s += srow[c] * ew[c * 8 + j];
  out[idx] = s;
}

// ---------------------------------------------------------------------------
extern "C" void kernel_launch(void* const* d_in, const int* in_sizes, int n_in,
                              void* d_out, int out_size, void* d_ws, size_t ws_size,
                              hipStream_t stream)
{
  const float* audio     = (const float*)d_in[0];
  const float* spect     = (const float*)d_in[1];
  const float* start_w   = (const float*)d_in[2];
  const float* start_b   = (const float*)d_in[3];
  const float* in_w      = (const float*)d_in[4];
  const float* in_b      = (const float*)d_in[5];
  const float* cond_w    = (const float*)d_in[6];
  const float* cond_b    = (const float*)d_in[7];
  const float* rs_w      = (const float*)d_in[8];
  const float* rs_b      = (const float*)d_in[9];
  const float* rs_w_last = (const float*)d_in[10];
  const float* rs_b_last = (const float*)d_in[11];
  const float* end_w     = (const float*)d_in[12];
  const float* end_b     = (const float*)d_in[13];
  float* out = (float*)d_out;

  char* p = (char*)d_ws;
  bf16* spect_bf = (bf16*)p;  p += (size_t)BTROWS * NMEL * 2;          // 83.9 MB
  bf16* hpad     = (bf16*)p;  p += (size_t)NBATCH * 32 * TPAD * 8 * 2; // 35.7 MB
  bf16* actsb    = (bf16*)p;  p += (size_t)BTROWS * NCH * 2;           // 33.6 MB
  float* skip    = (float*)p; p += (size_t)BTROWS * NCH * 4;           // 67.1 MB
  bf16* wx       = (bf16*)p;  p += (size_t)LAYERS * 512 * KX * 2;      // 11.5 MB
  bf16* wr       = (bf16*)p;  p += (size_t)LAYERS * 512 * 256 * 2;     //  2.1 MB
  float* xb      = (float*)p; p += (size_t)LAYERS * 512 * 4;
  float* rb      = (float*)p; p += (size_t)LAYERS * 512 * 4;
  if ((size_t)(p - (char*)d_ws) > ws_size) return;  // insufficient workspace

  hipMemsetAsync(hpad, 0, (size_t)NBATCH * 32 * TPAD * 8 * 2, stream);
  prep_wx_kernel<<<(LAYERS * 512 * KX + 255) / 256, 256, 0, stream>>>(in_w, cond_w, wx);
  prep_wr_kernel<<<(LAYERS * 512 * 256) / 256, 256, 0, stream>>>(rs_w, rs_w_last, wr);
  prep_bias_kernel<<<16, 256, 0, stream>>>(in_b, cond_b, rs_b, rs_b_last, xb, rb);
  cvt_spect_kernel<<<(BTROWS * NMEL) / 256, 256, 0, stream>>>(spect, spect_bf);
  start_kernel<<<(BTROWS * NCH) / 256, 256, 0, stream>>>(audio, start_w, start_b, hpad);

  for (int i = 0; i < LAYERS; ++i) {
    gemm1_kernel<<<512, 512, 0, stream>>>(hpad, spect_bf, wx + (size_t)i * 44 * 4 * 512 * 8,
                                          xb + i * 512, actsb, 1 << i);
    gemm2_kernel<<<512, 512, 0, stream>>>(actsb, wr + (size_t)i * 8 * 4 * 512 * 8,
                                          rb + i * 512, hpad, skip, i == 0 ? 1 : 0);
  }
  end_kernel<<<(BTROWS * 8) / 256, 256, 0, stream>>>(skip, end_w, end_b, out);
}

// Round 7
// 1618.981 us; speedup vs baseline: 1.4203x; 1.0602x over previous
//
#include <hip/hip_runtime.h>
#include <hip/hip_bf16.h>
#include <stdint.h>
#include <stddef.h>

#define LAYERS 8
#define NCH 256
#define NMEL 640
#define NBATCH 16
#define SEQT 4096
#define BTROWS (NBATCH * SEQT)   // 65536
#define PADT 128
#define TPAD (SEQT + 2 * PADT)   // 4352
#define KX 1408                  // 3*256 + 640

// NC8 layouts (all bf16, inner dim = 8 channels/k):
//  hpad : [b][32 cc][TPAD t][8]
//  spect: [b][80 cc][4096 t][8]
//  acts : [b][32 cc][4096 t][8]
//  wx   : [layer][44 kt][4 kc][512 n][8]
//  wr   : [layer][ 8 kt][4 kc][512 n][8]

typedef __hip_bfloat16 bf16;
typedef __attribute__((ext_vector_type(8))) short short8;
typedef __attribute__((ext_vector_type(4))) float f32x4;

__device__ __forceinline__ void g2l16(const void* g, void* l) {
  __builtin_amdgcn_global_load_lds(
      (const __attribute__((address_space(1))) unsigned int*)g,
      (__attribute__((address_space(3))) unsigned int*)l, 16, 0, 0);
}

#define VM8()   asm volatile("s_waitcnt vmcnt(8)"  ::: "memory")
#define VM0()   asm volatile("s_waitcnt vmcnt(0)"  ::: "memory")
#define LGKM0() asm volatile("s_waitcnt lgkmcnt(0)" ::: "memory")

__device__ __forceinline__ float fsigmoid(float x) { return 1.f / (1.f + __expf(-x)); }
__device__ __forceinline__ float ftanh_(float x) { return 1.f - 2.f / (__expf(2.f * x) + 1.f); }
__device__ __forceinline__ float bf2f(unsigned short u) {
  unsigned x = ((unsigned)u) << 16; float f; __builtin_memcpy(&f, &x, 4); return f;
}

// ---------------------------------------------------------------------------
// GEMM1: x = [h(t-d); h(t); h(t+d); spect] @ Wstack^T ; acts = tanh(x1)*sig(x2)
// 256 rows x (128 tanh + 128 paired sigmoid cols). 8 waves (4m x 2n).
// R5-proven sync template, BK=64/phase (2 chunks), ring-2 64KB slots:
//   phase p: stage(p+1)[8 loads] ; VM8 ; bar ; read kk0 ; LGKM0 ; SB ;
//            MFMA kk0 ; read kk1 ; LGKM0 ; SB ; bar ; MFMA kk1
// Slot (p+1)&1 overwritten only after bar(2,p-1), whose LGKM0 retired all its
// reads -- the R5 invariant. VM8 leaves only stage(p+1)'s 8 loads in flight.
// ---------------------------------------------------------------------------
__global__ __launch_bounds__(512, 2) void gemm1_kernel(
    const bf16* __restrict__ hpad, const bf16* __restrict__ spect,
    const bf16* __restrict__ wx,   // this layer: [44][4][512][8]
    const float* __restrict__ xb,  // [512] combined in_b + cond_b
    bf16* __restrict__ acts, int dil)
{
  // per slot (shorts): A [8 kc][256 t][8]=16384, B1 [8][128][8]=8192, B2 8192
  __shared__ alignas(16) short lds[2 * 32768];   // 128 KB

  const int tid  = threadIdx.x;
  const int lane = tid & 63;
  const int wid  = tid >> 6;
  const int wm   = wid >> 1;          // 0..3
  const int wn   = wid & 1;           // 0..1

  const int wg  = blockIdx.x;
  const int swz = ((wg & 7) << 6) | (wg >> 3);   // bijective on [0,512)
  const int m0 = (swz >> 1) * 256;
  const int c0 = (swz & 1) * 128;     // tanh channel tile: 0 or 128
  const int b  = m0 >> 12;            // tile fully inside one batch
  const int t0 = m0 & (SEQT - 1);

  const f32x4 fzero = {0.f, 0.f, 0.f, 0.f};
  f32x4 acc1[4][4], acc2[4][4];
#pragma unroll
  for (int i = 0; i < 4; ++i)
#pragma unroll
    for (int j = 0; j < 4; ++j) { acc1[i][j] = fzero; acc2[i][j] = fzero; }

  // staging decomposition: A by (ccA, tA), B by (kcB, nB); lanes contiguous
  const int tA  = tid & 127;
  const int ccA = tid >> 7;           // 0..3
  const int nB  = tid & 127;
  const int kcB = tid >> 7;           // 0..3

  const bf16* pAh = hpad  + (((size_t)b * 32 + ccA) * TPAD + PADT + t0 + tA) * 8;
  const bf16* pAs = spect + (((size_t)b * 80 + ccA) * 4096 + t0 + tA) * 8;
  const bf16* pB  = wx + ((size_t)(kcB * 512) + c0 + nB) * 8;
  const ptrdiff_t dil8 = (ptrdiff_t)dil * 8;

  auto stage1 = [&](int kt, short* base, int sub) {
    const bf16* a0;
    if (kt < 24) {
      const int tap = kt >> 3;                       // 0,1,2
      a0 = pAh + (ptrdiff_t)((kt & 7) * 4) * TPAD * 8 + (ptrdiff_t)(tap - 1) * dil8;
    } else {
      a0 = pAs + (ptrdiff_t)(kt - 24) * 131072;      // 4*4096*8
    }
    const bf16* w1 = pB + (ptrdiff_t)kt * 16384;     // 4*512*8
    g2l16(a0,        base + ((sub * 4 + ccA) * 256 + tA) * 8);
    g2l16(a0 + 1024, base + ((sub * 4 + ccA) * 256 + tA + 128) * 8);
    g2l16(w1,        base + 16384 + ((sub * 4 + kcB) * 128 + nB) * 8);
    g2l16(w1 + 2048, base + 24576 + ((sub * 4 + kcB) * 128 + nB) * 8);
  };
  auto stage = [&](int p) {
    short* base = lds + (p & 1) * 32768;
    stage1(2 * p,     base, 0);
    stage1(2 * p + 1, base, 1);
  };

  const int rl = lane & 15;
  const int kc = lane >> 4;

  auto ldsread = [&](const short* cur, int kk,
                     short8 (&af)[4], short8 (&bfa)[4], short8 (&bfb)[4]) {
    const int kc2 = kk * 4 + kc;      // 0..7
#pragma unroll
    for (int f = 0; f < 4; ++f) {
      af[f]  = *(const short8*)(cur + (kc2 * 256 + wm * 64 + f * 16 + rl) * 8);
      bfa[f] = *(const short8*)(cur + 16384 + (kc2 * 128 + wn * 64 + f * 16 + rl) * 8);
      bfb[f] = *(const short8*)(cur + 24576 + (kc2 * 128 + wn * 64 + f * 16 + rl) * 8);
    }
  };
  auto domfma = [&](const short8 (&af)[4], const short8 (&bfa)[4], const short8 (&bfb)[4]) {
    __builtin_amdgcn_s_setprio(1);
#pragma unroll
    for (int i = 0; i < 4; ++i)
#pragma unroll
      for (int j = 0; j < 4; ++j) {
        acc1[i][j] = __builtin_amdgcn_mfma_f32_16x16x32_bf16(af[i], bfa[j], acc1[i][j], 0, 0, 0);
        acc2[i][j] = __builtin_amdgcn_mfma_f32_16x16x32_bf16(af[i], bfb[j], acc2[i][j], 0, 0, 0);
      }
    __builtin_amdgcn_s_setprio(0);
  };

  auto phase = [&](int p, bool pf) {
    if (pf) { stage(p + 1); VM8(); }
    else    { VM0(); }
    __builtin_amdgcn_s_barrier();      // slot p&1 fully staged
    const short* cur = lds + (p & 1) * 32768;
    short8 a_[4], b1_[4], b2_[4];
    ldsread(cur, 0, a_, b1_, b2_);
    LGKM0();
    __builtin_amdgcn_sched_barrier(0);
    domfma(a_, b1_, b2_);
    ldsread(cur, 1, a_, b1_, b2_);
    LGKM0();
    __builtin_amdgcn_sched_barrier(0);
    __builtin_amdgcn_s_barrier();      // all reads of slot p&1 retired
    domfma(a_, b1_, b2_);
  };

  stage(0);
  for (int p = 0; p < 21; ++p) phase(p, true);
  phase(21, false);

  const int rl2 = lane & 15;
  const int ro  = (lane >> 4) * 4;
#pragma unroll
  for (int i = 0; i < 4; ++i) {
#pragma unroll
    for (int j = 0; j < 4; ++j) {
      const int col = c0 + wn * 64 + j * 16 + rl2;   // tanh channel, [0,256)
      const float bx1 = xb[col];
      const float bx2 = xb[col + 256];
      bf16* arow = acts + (((size_t)b * 32 + (col >> 3)) * 4096) * 8 + (col & 7);
#pragma unroll
      for (int r = 0; r < 4; ++r) {
        const int t = t0 + wm * 64 + i * 16 + ro + r;
        const float x1 = acc1[i][j][r] + bx1;
        const float x2 = acc2[i][j][r] + bx2;
        arow[(size_t)t * 8] = __float2bfloat16(ftanh_(x1) * fsigmoid(x2));
      }
    }
  }
}

// ---------------------------------------------------------------------------
// GEMM2: rs = acts @ Wr^T (+rb); n-half 0 -> h += rs ; half 1 -> skip (+)= rs
// 256 rows x 256 cols, 8 waves (4m x 2n), wave 64x128. Same template, BK=64.
// skip kept in bf16 (error << threshold margin; halves skip RMW traffic).
// ---------------------------------------------------------------------------
__global__ __launch_bounds__(512, 2) void gemm2_kernel(
    const bf16* __restrict__ acts, const bf16* __restrict__ wr,  // [8][4][512][8]
    const float* __restrict__ rb, bf16* __restrict__ hpad,
    bf16* __restrict__ skip, const int first)
{
  // per slot (shorts): A [8][256][8]=16384, B [8][256][8]=16384
  __shared__ alignas(16) short lds[2 * 32768];   // 128 KB

  const int tid  = threadIdx.x;
  const int lane = tid & 63;
  const int wid  = tid >> 6;
  const int wm   = wid >> 1;          // 0..3
  const int wn   = wid & 1;           // 0..1

  const int wg  = blockIdx.x;
  const int swz = ((wg & 7) << 6) | (wg >> 3);
  const int m0 = (swz >> 1) * 256;
  const int n0 = (swz & 1) * 256;     // 0 (h-update) or 256 (skip)
  const int b  = m0 >> 12;
  const int t0 = m0 & (SEQT - 1);

  const f32x4 fzero = {0.f, 0.f, 0.f, 0.f};
  f32x4 acc[4][8];
#pragma unroll
  for (int i = 0; i < 4; ++i)
#pragma unroll
    for (int j = 0; j < 8; ++j) acc[i][j] = fzero;

  const int tA   = tid & 127;
  const int ccA  = tid >> 7;          // 0..3
  const int nB2  = tid & 255;
  const int kcB2 = tid >> 8;          // 0..1 (loads kcB2 and kcB2+2)

  const bf16* pA = acts + (((size_t)b * 32 + ccA) * 4096 + t0 + tA) * 8;
  const bf16* pB = wr + ((size_t)(kcB2 * 512) + n0 + nB2) * 8;

  auto stage1 = [&](int kt, short* base, int sub) {
    const bf16* a0 = pA + (ptrdiff_t)kt * 131072;    // 4*4096*8
    const bf16* w0 = pB + (ptrdiff_t)kt * 16384;     // 4*512*8
    g2l16(a0,        base + ((sub * 4 + ccA) * 256 + tA) * 8);
    g2l16(a0 + 1024, base + ((sub * 4 + ccA) * 256 + tA + 128) * 8);
    g2l16(w0,        base + 16384 + ((sub * 4 + kcB2) * 256 + nB2) * 8);
    g2l16(w0 + 8192, base + 16384 + ((sub * 4 + kcB2 + 2) * 256 + nB2) * 8);
  };
  auto stage = [&](int p) {
    short* base = lds + (p & 1) * 32768;
    stage1(2 * p,     base, 0);
    stage1(2 * p + 1, base, 1);
  };

  const int rl = lane & 15;
  const int kc = lane >> 4;

  auto ldsread = [&](const short* cur, int kk, short8 (&af)[4], short8 (&bfr)[8]) {
    const int kc2 = kk * 4 + kc;
#pragma unroll
    for (int f = 0; f < 4; ++f)
      af[f] = *(const short8*)(cur + (kc2 * 256 + wm * 64 + f * 16 + rl) * 8);
#pragma unroll
    for (int j = 0; j < 8; ++j)
      bfr[j] = *(const short8*)(cur + 16384 + (kc2 * 256 + wn * 128 + j * 16 + rl) * 8);
  };
  auto domfma = [&](const short8 (&af)[4], const short8 (&bfr)[8]) {
    __builtin_amdgcn_s_setprio(1);
#pragma unroll
    for (int i = 0; i < 4; ++i)
#pragma unroll
      for (int j = 0; j < 8; ++j)
        acc[i][j] = __builtin_amdgcn_mfma_f32_16x16x32_bf16(af[i], bfr[j], acc[i][j], 0, 0, 0);
    __builtin_amdgcn_s_setprio(0);
  };

  auto phase = [&](int p, bool pf) {
    if (pf) { stage(p + 1); VM8(); }
    else    { VM0(); }
    __builtin_amdgcn_s_barrier();
    const short* cur = lds + (p & 1) * 32768;
    short8 a_[4], b_[8];
    ldsread(cur, 0, a_, b_);
    LGKM0();
    __builtin_amdgcn_sched_barrier(0);
    domfma(a_, b_);
    ldsread(cur, 1, a_, b_);
    LGKM0();
    __builtin_amdgcn_sched_barrier(0);
    __builtin_amdgcn_s_barrier();
    domfma(a_, b_);
  };

  stage(0);
  for (int p = 0; p < 3; ++p) phase(p, true);
  phase(3, false);

  const int rl2 = lane & 15;
  const int ro  = (lane >> 4) * 4;
#pragma unroll
  for (int i = 0; i < 4; ++i) {
#pragma unroll
    for (int j = 0; j < 8; ++j) {
      const int n = n0 + wn * 128 + j * 16 + rl2;
      const float bias = rb[n];
#pragma unroll
      for (int r = 0; r < 4; ++r) {
        const int t = t0 + wm * 64 + i * 16 + ro + r;
        const float v = acc[i][j][r] + bias;
        if (n < NCH) {
          bf16* hp = hpad + ((((size_t)b * 32 + (n >> 3)) * TPAD + PADT + t) * 8) + (n & 7);
          *hp = __float2bfloat16(__bfloat162float(*hp) + v);
        } else {
          const size_t si = ((size_t)(b * SEQT + t)) * NCH + (n - NCH);
          if (first) skip[si] = __float2bfloat16(v);
          else       skip[si] = __float2bfloat16(__bfloat162float(skip[si]) + v);
        }
      }
    }
  }
}

// ---------------------------------------------------------------------------
// aux kernels
// ---------------------------------------------------------------------------
__global__ void start_kernel(const float* __restrict__ audio, const float* __restrict__ sw,
                             const float* __restrict__ sb, bf16* __restrict__ hpad)
{
  const int idx = blockIdx.x * 256 + threadIdx.x;   // < 16777216
  const int w  = idx & 7;
  const int t  = (idx >> 3) & 4095;
  const int cc = (idx >> 15) & 31;
  const int b  = idx >> 20;
  const int c  = cc * 8 + w;
  const float* a = audio + ((size_t)(b * SEQT + t)) * 4;
  float v = sb[c] + a[0] * sw[c] + a[1] * sw[256 + c] + a[2] * sw[512 + c] + a[3] * sw[768 + c];
  hpad[(((size_t)b * 32 + cc) * TPAD + PADT + t) * 8 + w] = __float2bfloat16(v);
}

__global__ void cvt_spect_kernel(const float* __restrict__ s, bf16* __restrict__ d)
{
  const size_t idx = (size_t)blockIdx.x * 256 + threadIdx.x;  // < 41943040
  const int w  = (int)(idx & 7);
  const int t  = (int)((idx >> 3) & 4095);
  const unsigned q = (unsigned)(idx >> 15);     // b*80 + cc
  const int b  = q / 80;
  const int cc = q % 80;
  const int c  = cc * 8 + w;
  d[idx] = __float2bfloat16(s[((size_t)(b * SEQT + t)) * NMEL + c]);
}

__global__ void prep_wx_kernel(const float* __restrict__ in_w, const float* __restrict__ cond_w,
                               bf16* __restrict__ wx)
{
  const size_t idx = (size_t)blockIdx.x * 256 + threadIdx.x;
  if (idx >= (size_t)LAYERS * 44 * 4 * 512 * 8) return;
  const int w   = (int)(idx & 7);
  const int n   = (int)((idx >> 3) & 511);
  const int kc  = (int)((idx >> 12) & 3);
  const unsigned ktp = (unsigned)(idx >> 14);   // i*44 + kt
  const int i  = ktp / 44;
  const int kt = ktp % 44;
  const int k  = kt * 32 + kc * 8 + w;
  float v;
  if (k < 768) {
    const int tap = k >> 8;
    const int c   = k & 255;
    v = in_w[(size_t)(((i * 3 + tap) << 8) + c) * 512 + n];
  } else {
    v = cond_w[((size_t)i * NMEL + (k - 768)) * 512 + n];
  }
  wx[idx] = __float2bfloat16(v);
}

__global__ void prep_wr_kernel(const float* __restrict__ rs_w, const float* __restrict__ rs_w_last,
                               bf16* __restrict__ wr)
{
  const int idx = blockIdx.x * 256 + threadIdx.x;   // < 1048576
  const int w  = idx & 7;
  const int n  = (idx >> 3) & 511;
  const int kc = (idx >> 12) & 3;
  const int kt = (idx >> 14) & 7;
  const int i  = idx >> 17;
  const int k  = kt * 32 + kc * 8 + w;              // [0,256)
  float v;
  if (i < LAYERS - 1) v = rs_w[(size_t)((i << 8) + k) * 512 + n];
  else                v = (n >= 256) ? rs_w_last[(k << 8) + (n - 256)] : 0.f;
  wr[idx] = __float2bfloat16(v);
}

__global__ void prep_bias_kernel(const float* __restrict__ in_b, const float* __restrict__ cond_b,
                                 const float* __restrict__ rs_b, const float* __restrict__ rs_b_last,
                                 float* __restrict__ xb, float* __restrict__ rb)
{
  const int idx = blockIdx.x * 256 + threadIdx.x;   // < 4096
  if (idx >= LAYERS * 512) return;
  const int i = idx >> 9;
  const int n = idx & 511;
  xb[idx] = in_b[idx] + cond_b[idx];
  rb[idx] = (i < LAYERS - 1) ? rs_b[idx] : ((n >= 256) ? rs_b_last[n - 256] : 0.f);
}

__global__ void end_kernel(const bf16* __restrict__ skip, const float* __restrict__ ew,
                           const float* __restrict__ eb, float* __restrict__ out)
{
  const int idx = blockIdx.x * 256 + threadIdx.x;   // < 524288
  const int m = idx >> 3;
  const int j = idx & 7;
  const bf16* srow = skip + (size_t)m * NCH;
  float s = eb[j];
#pragma unroll 4
  for (int c8 = 0; c8 < NCH / 8; ++c8) {
    short8 v = *(const short8*)(srow + c8 * 8);
#pragma unroll
    for (int w = 0; w < 8; ++w)
      s += bf2f((unsigned short)v[w]) * ew[(c8 * 8 + w) * 8 + j];
  }
  out[idx] = s;
}

// ---------------------------------------------------------------------------
extern "C" void kernel_launch(void* const* d_in, const int* in_sizes, int n_in,
                              void* d_out, int out_size, void* d_ws, size_t ws_size,
                              hipStream_t stream)
{
  const float* audio     = (const float*)d_in[0];
  const float* spect     = (const float*)d_in[1];
  const float* start_w   = (const float*)d_in[2];
  const float* start_b   = (const float*)d_in[3];
  const float* in_w      = (const float*)d_in[4];
  const float* in_b      = (const float*)d_in[5];
  const float* cond_w    = (const float*)d_in[6];
  const float* cond_b    = (const float*)d_in[7];
  const float* rs_w      = (const float*)d_in[8];
  const float* rs_b      = (const float*)d_in[9];
  const float* rs_w_last = (const float*)d_in[10];
  const float* rs_b_last = (const float*)d_in[11];
  const float* end_w     = (const float*)d_in[12];
  const float* end_b     = (const float*)d_in[13];
  float* out = (float*)d_out;

  char* p = (char*)d_ws;
  bf16* spect_bf = (bf16*)p;  p += (size_t)BTROWS * NMEL * 2;          // 83.9 MB
  bf16* hpad     = (bf16*)p;  p += (size_t)NBATCH * 32 * TPAD * 8 * 2; // 35.7 MB
  bf16* actsb    = (bf16*)p;  p += (size_t)BTROWS * NCH * 2;           // 33.6 MB
  bf16* skip     = (bf16*)p;  p += (size_t)BTROWS * NCH * 2;           // 33.6 MB
  bf16* wx       = (bf16*)p;  p += (size_t)LAYERS * 512 * KX * 2;      // 11.5 MB
  bf16* wr       = (bf16*)p;  p += (size_t)LAYERS * 512 * 256 * 2;     //  2.1 MB
  float* xb      = (float*)p; p += (size_t)LAYERS * 512 * 4;
  float* rb      = (float*)p; p += (size_t)LAYERS * 512 * 4;
  if ((size_t)(p - (char*)d_ws) > ws_size) return;  // insufficient workspace

  hipMemsetAsync(hpad, 0, (size_t)NBATCH * 32 * TPAD * 8 * 2, stream);
  prep_wx_kernel<<<(LAYERS * 512 * KX + 255) / 256, 256, 0, stream>>>(in_w, cond_w, wx);
  prep_wr_kernel<<<(LAYERS * 512 * 256) / 256, 256, 0, stream>>>(rs_w, rs_w_last, wr);
  prep_bias_kernel<<<16, 256, 0, stream>>>(in_b, cond_b, rs_b, rs_b_last, xb, rb);
  cvt_spect_kernel<<<(BTROWS * NMEL) / 256, 256, 0, stream>>>(spect, spect_bf);
  start_kernel<<<(BTROWS * NCH) / 256, 256, 0, stream>>>(audio, start_w, start_b, hpad);

  for (int i = 0; i < LAYERS; ++i) {
    gemm1_kernel<<<512, 512, 0, stream>>>(hpad, spect_bf, wx + (size_t)i * 44 * 4 * 512 * 8,
                                          xb + i * 512, actsb, 1 << i);
    gemm2_kernel<<<512, 512, 0, stream>>>(actsb, wr + (size_t)i * 8 * 4 * 512 * 8,
                                          rb + i * 512, hpad, skip, i == 0 ? 1 : 0);
  }
  end_kernel<<<(BTROWS * 8) / 256, 256, 0, stream>>>(skip, end_w, end_b, out);
}